// Round 3
// baseline (135.000 us; speedup 1.0000x reference)
//
#include <hip/hip_runtime.h>

#define NG   8192
#define NSH  4
#define HH   1024
#define WW   1024
#define PP   48            // footprint: x in [bx-24, bx+23]
#define TILE 16
#define TX   (WW / TILE)   // 64
#define TY   (HH / TILE)   // 64
#define NTILES (TX * TY)   // 4096
#define CAP  128           // per-tile list capacity; expected max ~55 (mean 31, sigma 5.6)
#define S_MIN (1.0f / 30.0f)
#define S_MAX (1.0f / 0.75f)
#define TWO_PI 6.28318530717958647692f
#define AEXP 0.8493218002880191f   // sqrt(log2(e)/2): folds exp->exp2 into S

// d_ws layout:
//   counts : NTILES int                      (16 KB, memset 0 each call)
//   lists  : NTILES * CAP * 3 float4         (~25 MB) fat entries:
//     e0 = {mu_px, mu_py, A0, A1}      A = AEXP*S0*(c, s)    (row 1 of scaled S R^T)
//     e1 = {B0, B1, op, r}             B = AEXP*S1*(-s, c)   (row 2)
//     e2 = {g, b, asint(bx), asint(by)}

__global__ void prep_bin_kernel(const float* __restrict__ xyz,
                                const float* __restrict__ feat,
                                const float* __restrict__ opac,
                                const float* __restrict__ scal,
                                const float* __restrict__ rot,
                                int* __restrict__ counts,
                                float4* __restrict__ lists) {
    int g = blockIdx.x * blockDim.x + threadIdx.x;
    if (g >= NG) return;

    float mx = fminf(fmaxf(xyz[2 * g + 0], -1.0f), 1.0f) * 1.05f;
    float my = fminf(fmaxf(xyz[2 * g + 1], -1.0f), 1.0f) * 1.05f;
    float s0 = fminf(fmaxf(scal[2 * g + 0], 0.0f), 1.0f) * (S_MAX - S_MIN) + S_MIN;
    float s1 = fminf(fmaxf(scal[2 * g + 1], 0.0f), 1.0f) * (S_MAX - S_MIN) + S_MIN;
    float rr = rot[g];
    float ang = (rr - floorf(rr)) * TWO_PI;
    float op = fminf(fmaxf(opac[g], 0.0f), 1.0f);

    float c, s;
    __sincosf(ang, &s, &c);

    // circular harmonics via angle-addition recurrence (one sincos total)
    const float* f = feat + g * (2 * NSH + 1) * 3;
    float r = f[0], gg = f[1], b = f[2];
    float sk = s, ck = c;
    #pragma unroll
    for (int i = 1; i <= NSH; ++i) {
        int ms = (2 * i - 1) * 3, mc = (2 * i) * 3;
        r  += sk * f[ms + 0] + ck * f[mc + 0];
        gg += sk * f[ms + 1] + ck * f[mc + 1];
        b  += sk * f[ms + 2] + ck * f[mc + 2];
        float sn = sk * c + ck * s;
        float cn = ck * c - sk * s;
        sk = sn; ck = cn;
    }

    float mu_px = (mx + 1.0f) * 0.5f * (float)(WW - 1);
    float mu_py = (my + 1.0f) * 0.5f * (float)(HH - 1);
    int bx = (int)floorf(mu_px), by = (int)floorf(mu_py);

    // clipped tile range of the 48x48 footprint
    int x0 = bx - PP / 2, x1 = bx + PP / 2 - 1;
    int y0 = by - PP / 2, y1 = by + PP / 2 - 1;
    if (x1 < 0 || x0 > WW - 1 || y1 < 0 || y0 > HH - 1) return;
    int tx0 = max(x0, 0) / TILE, tx1 = min(x1, WW - 1) / TILE;
    int ty0 = max(y0, 0) / TILE, ty1 = min(y1, HH - 1) / TILE;

    float a0 = AEXP * s0, a1 = AEXP * s1;
    float4 e0 = make_float4(mu_px, mu_py, a0 * c, a0 * s);
    float4 e1 = make_float4(-a1 * s, a1 * c, op, r);
    float4 e2 = make_float4(gg, b, __int_as_float(bx), __int_as_float(by));

    for (int ty = ty0; ty <= ty1; ++ty)
        for (int tx = tx0; tx <= tx1; ++tx) {
            int t = ty * TX + tx;
            int pos = atomicAdd(&counts[t], 1);
            if (pos < CAP) {
                float4* dst = lists + ((size_t)t * CAP + pos) * 3;
                dst[0] = e0;
                dst[1] = e1;
                dst[2] = e2;
            }
        }
}

__global__ void __launch_bounds__(256)
render_kernel(const int* __restrict__ counts,
              const float4* __restrict__ lists,
              float* __restrict__ out) {
    int tile = blockIdx.x;
    int tx = tile & (TX - 1), ty = tile / TX;
    int lx = threadIdx.x & (TILE - 1), ly = threadIdx.x / TILE;
    int px = tx * TILE + lx, py = ty * TILE + ly;
    float fpx = (float)px, fpy = (float)py;

    int n = min(counts[tile], CAP);
    const float4* gp = lists + (size_t)tile * CAP * 3;

    float fr = 0.f, fg = 0.f, fb = 0.f, fw = 0.f;

    for (int j = 0; j < n; ++j) {
        float4 e0 = gp[3 * j + 0];
        float4 e1 = gp[3 * j + 1];
        float4 e2 = gp[3 * j + 2];
        int bx = __float_as_int(e2.z);
        int by = __float_as_int(e2.w);
        unsigned ox = (unsigned)(px - bx + PP / 2);
        unsigned oy = (unsigned)(py - by + PP / 2);
        if ((ox < PP) & (oy < PP)) {
            float dx = fpx - e0.x;
            float dy = fpy - e0.y;
            float vx = e0.z * dx + e0.w * dy;
            float vy = e1.x * dx + e1.y * dy;
            float t = fmaf(vx, vx, vy * vy);
            float w = e1.z * exp2f(-t);
            fr += w * e1.w;
            fg += w * e2.x;
            fb += w * e2.y;
            fw += w;
        }
    }

    float inv = 1.0f / (fw + 1e-6f);
    int idx = py * WW + px;
    out[3 * idx + 0] = fr * inv;
    out[3 * idx + 1] = fg * inv;
    out[3 * idx + 2] = fb * inv;
}

extern "C" void kernel_launch(void* const* d_in, const int* in_sizes, int n_in,
                              void* d_out, int out_size, void* d_ws, size_t ws_size,
                              hipStream_t stream) {
    const float* xyz  = (const float*)d_in[0];
    const float* feat = (const float*)d_in[1];
    const float* opac = (const float*)d_in[2];
    const float* scal = (const float*)d_in[3];
    const float* rot  = (const float*)d_in[4];
    float* out = (float*)d_out;

    char* ws = (char*)d_ws;
    int* counts = (int*)ws;
    float4* lists = (float4*)(ws + 65536);   // 64 KB aligned past counts

    hipMemsetAsync(counts, 0, (size_t)NTILES * sizeof(int), stream);
    prep_bin_kernel<<<NG / 256, 256, 0, stream>>>(xyz, feat, opac, scal, rot,
                                                  counts, lists);
    render_kernel<<<NTILES, 256, 0, stream>>>(counts, lists, out);
}

// Round 4
// 92.924 us; speedup vs baseline: 1.4528x; 1.4528x over previous
//
#include <hip/hip_runtime.h>

#define NG   8192
#define NSH  4
#define HH   1024
#define WW   1024
#define PP   48            // footprint: x in [bx-24, bx+23]
#define TILE 16
#define TX   (WW / TILE)   // 64
#define TY   (HH / TILE)   // 64
#define NTILES (TX * TY)   // 4096
#define CAP  128           // per-tile list capacity; mean ~31, 12-sigma safe
#define S_MIN (1.0f / 30.0f)
#define S_MAX (1.0f / 0.75f)
#define TWO_PI 6.28318530717958647692f
#define AEXP 0.8493218002880191f   // sqrt(log2(e)/2): folds exp->exp2 into S

// d_ws layout:
//   counts : NTILES int   (16 KB)  -- zeroed by prep_kernel each call
//   ranges : NG uint      (32 KB)  -- packed tx0|ty0<<8|nx<<16|ny<<20 (0 = offscreen)
//   params : NG * 3 float4 (384 KB):
//     e0 = {mu_px, mu_py, A0, A1}      A = AEXP*S0*(c, s)
//     e1 = {B0, B1, op, r}             B = AEXP*S1*(-s, c)
//     e2 = {g, b, asint(bx), asint(by)}
//   list   : NTILES * CAP int (2 MB)

__global__ void prep_kernel(const float* __restrict__ xyz,
                            const float* __restrict__ feat,
                            const float* __restrict__ opac,
                            const float* __restrict__ scal,
                            const float* __restrict__ rot,
                            int* __restrict__ counts,
                            unsigned* __restrict__ ranges,
                            float4* __restrict__ params) {
    int g = blockIdx.x * blockDim.x + threadIdx.x;
    if (g < NTILES) counts[g] = 0;   // bin_kernel runs after us; no memset node needed
    if (g >= NG) return;

    float mx = fminf(fmaxf(xyz[2 * g + 0], -1.0f), 1.0f) * 1.05f;
    float my = fminf(fmaxf(xyz[2 * g + 1], -1.0f), 1.0f) * 1.05f;
    float s0 = fminf(fmaxf(scal[2 * g + 0], 0.0f), 1.0f) * (S_MAX - S_MIN) + S_MIN;
    float s1 = fminf(fmaxf(scal[2 * g + 1], 0.0f), 1.0f) * (S_MAX - S_MIN) + S_MIN;
    float rr = rot[g];
    float ang = (rr - floorf(rr)) * TWO_PI;
    float op = fminf(fmaxf(opac[g], 0.0f), 1.0f);

    float c, s;
    __sincosf(ang, &s, &c);

    // circular harmonics via angle-addition recurrence (one sincos total)
    const float* f = feat + g * (2 * NSH + 1) * 3;
    float r = f[0], gg = f[1], b = f[2];
    float sk = s, ck = c;
    #pragma unroll
    for (int i = 1; i <= NSH; ++i) {
        int ms = (2 * i - 1) * 3, mc = (2 * i) * 3;
        r  += sk * f[ms + 0] + ck * f[mc + 0];
        gg += sk * f[ms + 1] + ck * f[mc + 1];
        b  += sk * f[ms + 2] + ck * f[mc + 2];
        float sn = sk * c + ck * s;
        float cn = ck * c - sk * s;
        sk = sn; ck = cn;
    }

    float mu_px = (mx + 1.0f) * 0.5f * (float)(WW - 1);
    float mu_py = (my + 1.0f) * 0.5f * (float)(HH - 1);
    int bx = (int)floorf(mu_px), by = (int)floorf(mu_py);

    float a0 = AEXP * s0, a1 = AEXP * s1;
    params[3 * g + 0] = make_float4(mu_px, mu_py, a0 * c, a0 * s);
    params[3 * g + 1] = make_float4(-a1 * s, a1 * c, op, r);
    params[3 * g + 2] = make_float4(gg, b, __int_as_float(bx), __int_as_float(by));

    // clipped tile range of the 48x48 footprint (spans at most 4x4 tiles)
    int x0 = bx - PP / 2, x1 = bx + PP / 2 - 1;
    int y0 = by - PP / 2, y1 = by + PP / 2 - 1;
    unsigned pack = 0;
    if (!(x1 < 0 || x0 > WW - 1 || y1 < 0 || y0 > HH - 1)) {
        int tx0 = max(x0, 0) / TILE, tx1 = min(x1, WW - 1) / TILE;
        int ty0 = max(y0, 0) / TILE, ty1 = min(y1, HH - 1) / TILE;
        pack = (unsigned)tx0 | ((unsigned)ty0 << 8)
             | ((unsigned)(tx1 - tx0 + 1) << 16) | ((unsigned)(ty1 - ty0 + 1) << 20);
    }
    ranges[g] = pack;
}

// one thread per (gaussian, 4x4 candidate-tile slot): 131K threads
__global__ void bin_kernel(const unsigned* __restrict__ ranges,
                           int* __restrict__ counts,
                           int* __restrict__ list) {
    int t = blockIdx.x * blockDim.x + threadIdx.x;
    int g = t >> 4, slot = t & 15;
    unsigned rng = ranges[g];
    int nx = (rng >> 16) & 0xF, ny = (rng >> 20) & 0xF;
    int sx = slot & 3, sy = slot >> 2;
    if (sx >= nx || sy >= ny) return;
    int tx = (int)(rng & 0xFF) + sx;
    int ty = (int)((rng >> 8) & 0xFF) + sy;
    int tile = ty * TX + tx;
    int pos = atomicAdd(&counts[tile], 1);
    if (pos < CAP) list[tile * CAP + pos] = g;
}

__global__ void __launch_bounds__(256)
render_kernel(const int* __restrict__ counts,
              const int* __restrict__ list,
              const float4* __restrict__ params,
              float* __restrict__ out) {
    int tile = blockIdx.x;
    int tx = tile & (TX - 1), ty = tile / TX;
    int lx = threadIdx.x & (TILE - 1), ly = threadIdx.x / TILE;
    int px = tx * TILE + lx, py = ty * TILE + ly;
    float fpx = (float)px, fpy = (float)py;

    int n = min(counts[tile], CAP);

    __shared__ float4 sp[3 * CAP];
    for (int i = threadIdx.x; i < 3 * n; i += 256) {
        int gi = list[tile * CAP + i / 3];
        sp[i] = params[3 * gi + i % 3];
    }
    __syncthreads();

    float fr = 0.f, fg = 0.f, fb = 0.f, fw = 0.f;

    for (int j = 0; j < n; ++j) {
        float4 e0 = sp[3 * j + 0];
        float4 e1 = sp[3 * j + 1];
        float4 e2 = sp[3 * j + 2];
        int bx = __float_as_int(e2.z);
        int by = __float_as_int(e2.w);
        unsigned ox = (unsigned)(px - bx + PP / 2);
        unsigned oy = (unsigned)(py - by + PP / 2);
        if ((ox < PP) & (oy < PP)) {
            float dx = fpx - e0.x;
            float dy = fpy - e0.y;
            float vx = e0.z * dx + e0.w * dy;
            float vy = e1.x * dx + e1.y * dy;
            float t = fmaf(vx, vx, vy * vy);
            float w = e1.z * exp2f(-t);
            fr += w * e1.w;
            fg += w * e2.x;
            fb += w * e2.y;
            fw += w;
        }
    }

    float inv = 1.0f / (fw + 1e-6f);
    int idx = py * WW + px;
    out[3 * idx + 0] = fr * inv;
    out[3 * idx + 1] = fg * inv;
    out[3 * idx + 2] = fb * inv;
}

extern "C" void kernel_launch(void* const* d_in, const int* in_sizes, int n_in,
                              void* d_out, int out_size, void* d_ws, size_t ws_size,
                              hipStream_t stream) {
    const float* xyz  = (const float*)d_in[0];
    const float* feat = (const float*)d_in[1];
    const float* opac = (const float*)d_in[2];
    const float* scal = (const float*)d_in[3];
    const float* rot  = (const float*)d_in[4];
    float* out = (float*)d_out;

    char* ws = (char*)d_ws;
    size_t off = 0;
    int*      counts = (int*)(ws + off);      off += (size_t)NTILES * sizeof(int);
    unsigned* ranges = (unsigned*)(ws + off); off += (size_t)NG * sizeof(unsigned);
    float4*   params = (float4*)(ws + off);   off += (size_t)NG * 3 * sizeof(float4);
    int*      list   = (int*)(ws + off);

    prep_kernel<<<NG / 256, 256, 0, stream>>>(xyz, feat, opac, scal, rot,
                                              counts, ranges, params);
    bin_kernel<<<NG * 16 / 256, 256, 0, stream>>>(ranges, counts, list);
    render_kernel<<<NTILES, 256, 0, stream>>>(counts, list, params, out);
}

// Round 5
// 88.176 us; speedup vs baseline: 1.5310x; 1.0538x over previous
//
#include <hip/hip_runtime.h>

#define NG   8192
#define NSH  4
#define HH   1024
#define WW   1024
#define PP   48            // footprint: x in [bx-24, bx+23]
#define TILE 16
#define TX   (WW / TILE)   // 64
#define TY   (HH / TILE)   // 64
#define NTILES (TX * TY)   // 4096
#define CAP  128           // per-tile list capacity; mean ~31, 12-sigma safe
#define S_MIN (1.0f / 30.0f)
#define S_MAX (1.0f / 0.75f)
#define TWO_PI 6.28318530717958647692f
#define AEXP 0.8493218002880191f   // sqrt(log2(e)/2): folds exp->exp2 into S

#if __has_builtin(__builtin_amdgcn_exp2f)
#define EXP2F(x) __builtin_amdgcn_exp2f(x)
#else
#define EXP2F(x) exp2f(x)
#endif

// d_ws layout:
//   counts : NTILES int   (16 KB)  -- zeroed by prep_kernel each call
//   ranges : NG uint      (32 KB)  -- packed tx0|ty0<<8|nx<<16|ny<<20 (0 = offscreen)
//   params : NG * 3 float4 (384 KB):
//     e0 = {mu_px, mu_py, A0, A1}      A = AEXP*S0*(c, s)
//     e1 = {B0, B1, op, r}             B = AEXP*S1*(-s, c)
//     e2 = {g, b, asint(bx), asint(by)}
//   list   : NTILES * CAP int (2 MB)

__global__ void __launch_bounds__(64)
prep_kernel(const float* __restrict__ xyz,
            const float* __restrict__ feat,
            const float* __restrict__ opac,
            const float* __restrict__ scal,
            const float* __restrict__ rot,
            int* __restrict__ counts,
            unsigned* __restrict__ ranges,
            float4* __restrict__ params) {
    int g = blockIdx.x * blockDim.x + threadIdx.x;
    if (g < NTILES) counts[g] = 0;   // bin_kernel runs after us; no memset node needed
    if (g >= NG) return;

    float mx = fminf(fmaxf(xyz[2 * g + 0], -1.0f), 1.0f) * 1.05f;
    float my = fminf(fmaxf(xyz[2 * g + 1], -1.0f), 1.0f) * 1.05f;
    float s0 = fminf(fmaxf(scal[2 * g + 0], 0.0f), 1.0f) * (S_MAX - S_MIN) + S_MIN;
    float s1 = fminf(fmaxf(scal[2 * g + 1], 0.0f), 1.0f) * (S_MAX - S_MIN) + S_MIN;
    float rr = rot[g];
    float ang = (rr - floorf(rr)) * TWO_PI;
    float op = fminf(fmaxf(opac[g], 0.0f), 1.0f);

    float c, s;
    __sincosf(ang, &s, &c);

    // circular harmonics via angle-addition recurrence (one sincos total)
    const float* f = feat + g * (2 * NSH + 1) * 3;
    float r = f[0], gg = f[1], b = f[2];
    float sk = s, ck = c;
    #pragma unroll
    for (int i = 1; i <= NSH; ++i) {
        int ms = (2 * i - 1) * 3, mc = (2 * i) * 3;
        r  += sk * f[ms + 0] + ck * f[mc + 0];
        gg += sk * f[ms + 1] + ck * f[mc + 1];
        b  += sk * f[ms + 2] + ck * f[mc + 2];
        float sn = sk * c + ck * s;
        float cn = ck * c - sk * s;
        sk = sn; ck = cn;
    }

    float mu_px = (mx + 1.0f) * 0.5f * (float)(WW - 1);
    float mu_py = (my + 1.0f) * 0.5f * (float)(HH - 1);
    int bx = (int)floorf(mu_px), by = (int)floorf(mu_py);

    float a0 = AEXP * s0, a1 = AEXP * s1;
    params[3 * g + 0] = make_float4(mu_px, mu_py, a0 * c, a0 * s);
    params[3 * g + 1] = make_float4(-a1 * s, a1 * c, op, r);
    params[3 * g + 2] = make_float4(gg, b, __int_as_float(bx), __int_as_float(by));

    // clipped tile range of the 48x48 footprint (spans at most 4x4 tiles)
    int x0 = bx - PP / 2, x1 = bx + PP / 2 - 1;
    int y0 = by - PP / 2, y1 = by + PP / 2 - 1;
    unsigned pack = 0;
    if (!(x1 < 0 || x0 > WW - 1 || y1 < 0 || y0 > HH - 1)) {
        int tx0 = max(x0, 0) / TILE, tx1 = min(x1, WW - 1) / TILE;
        int ty0 = max(y0, 0) / TILE, ty1 = min(y1, HH - 1) / TILE;
        pack = (unsigned)tx0 | ((unsigned)ty0 << 8)
             | ((unsigned)(tx1 - tx0 + 1) << 16) | ((unsigned)(ty1 - ty0 + 1) << 20);
    }
    ranges[g] = pack;
}

// one thread per (gaussian, 4x4 candidate-tile slot): 131K threads
__global__ void bin_kernel(const unsigned* __restrict__ ranges,
                           int* __restrict__ counts,
                           int* __restrict__ list) {
    int t = blockIdx.x * blockDim.x + threadIdx.x;
    int g = t >> 4, slot = t & 15;
    unsigned rng = ranges[g];
    int nx = (rng >> 16) & 0xF, ny = (rng >> 20) & 0xF;
    int sx = slot & 3, sy = slot >> 2;
    if (sx >= nx || sy >= ny) return;
    int tx = (int)(rng & 0xFF) + sx;
    int ty = (int)((rng >> 8) & 0xFF) + sy;
    int tile = ty * TX + tx;
    int pos = atomicAdd(&counts[tile], 1);
    if (pos < CAP) list[tile * CAP + pos] = g;
}

// 64 threads/block, one 16x16 tile/block, 4 pixels/thread (rows ly0+4k)
__global__ void __launch_bounds__(64)
render_kernel(const int* __restrict__ counts,
              const int* __restrict__ list,
              const float4* __restrict__ params,
              float* __restrict__ out) {
    int tile = blockIdx.x;
    int tx = tile & (TX - 1), ty = tile / TX;
    int lx = threadIdx.x & (TILE - 1), ly0 = threadIdx.x >> 4;  // ly0 in [0,4)
    int px = tx * TILE + lx, py0 = ty * TILE + ly0;
    float fpx = (float)px, fpy0 = (float)py0;

    int n = min(counts[tile], CAP);

    __shared__ float4 sp[3 * CAP];
    for (int e = threadIdx.x; e < n; e += 64) {
        int gi = list[tile * CAP + e];
        sp[3 * e + 0] = params[3 * gi + 0];
        sp[3 * e + 1] = params[3 * gi + 1];
        sp[3 * e + 2] = params[3 * gi + 2];
    }
    __syncthreads();

    float fr[4] = {0.f, 0.f, 0.f, 0.f};
    float fg[4] = {0.f, 0.f, 0.f, 0.f};
    float fb[4] = {0.f, 0.f, 0.f, 0.f};
    float fw[4] = {0.f, 0.f, 0.f, 0.f};

    for (int j = 0; j < n; ++j) {
        float4 e0 = sp[3 * j + 0];
        float4 e1 = sp[3 * j + 1];
        float4 e2 = sp[3 * j + 2];
        int bx = __float_as_int(e2.z);
        int by = __float_as_int(e2.w);
        unsigned ox = (unsigned)(px - bx + PP / 2);
        if (ox < PP) {
            unsigned oy0 = (unsigned)(py0 - by + PP / 2);
            float dx = fpx - e0.x;
            float dy0 = fpy0 - e0.y;
            float vx0 = e0.z * dx + e0.w * dy0;   // A0*dx + A1*dy
            float vy0 = e1.x * dx + e1.y * dy0;   // B0*dx + B1*dy
            #pragma unroll
            for (int k = 0; k < 4; ++k) {
                if (oy0 + 4u * k < PP) {          // unsigned wrap handles by>py0 case
                    float fk = 4.0f * (float)k;
                    float vx = fmaf(fk, e0.w, vx0);
                    float vy = fmaf(fk, e1.y, vy0);
                    float w = e1.z * EXP2F(-fmaf(vx, vx, vy * vy));
                    fr[k] += w * e1.w;
                    fg[k] += w * e2.x;
                    fb[k] += w * e2.y;
                    fw[k] += w;
                }
            }
        }
    }

    #pragma unroll
    for (int k = 0; k < 4; ++k) {
        float inv = 1.0f / (fw[k] + 1e-6f);
        int idx = (py0 + 4 * k) * WW + px;
        out[3 * idx + 0] = fr[k] * inv;
        out[3 * idx + 1] = fg[k] * inv;
        out[3 * idx + 2] = fb[k] * inv;
    }
}

extern "C" void kernel_launch(void* const* d_in, const int* in_sizes, int n_in,
                              void* d_out, int out_size, void* d_ws, size_t ws_size,
                              hipStream_t stream) {
    const float* xyz  = (const float*)d_in[0];
    const float* feat = (const float*)d_in[1];
    const float* opac = (const float*)d_in[2];
    const float* scal = (const float*)d_in[3];
    const float* rot  = (const float*)d_in[4];
    float* out = (float*)d_out;

    char* ws = (char*)d_ws;
    size_t off = 0;
    int*      counts = (int*)(ws + off);      off += (size_t)NTILES * sizeof(int);
    unsigned* ranges = (unsigned*)(ws + off); off += (size_t)NG * sizeof(unsigned);
    float4*   params = (float4*)(ws + off);   off += (size_t)NG * 3 * sizeof(float4);
    int*      list   = (int*)(ws + off);

    prep_kernel<<<NG / 64, 64, 0, stream>>>(xyz, feat, opac, scal, rot,
                                            counts, ranges, params);
    bin_kernel<<<NG * 16 / 256, 256, 0, stream>>>(ranges, counts, list);
    render_kernel<<<NTILES, 64, 0, stream>>>(counts, list, params, out);
}